// Round 9
// baseline (106.891 us; speedup 1.0000x reference)
//
#include <hip/hip_runtime.h>
#include <math.h>

#define IMG 416
#define N_ANG 320
#define N_DET 416
#define N_SAMP 416

// ---------------------------------------------------------------------------
// Padded global fp8 image G: stride 464 B, 432 rows. Pixel (r,c) of the diff
// image lives at G[(r+8)*464 + (c+8)], zero outside [0,416)^2.
// ---------------------------------------------------------------------------
#define GSTRIDE 464
#define GROWS   432
#define GBYTES  ((size_t)GROWS * GSTRIDE)        // 200448
#define GWORDS  (GROWS * GSTRIDE / 4)            // 50112

#define SPLANE  (N_ANG * N_DET)                  // 133120 rays
#define SBYTES  ((size_t)4 * SPLANE * sizeof(float))
#define WSNEED  (GBYTES + SBYTES)

// LDS staged quadrant tile with ODD pitch 57 dwords (228 B): 57 mod 32 = 25,
// gcd(57,32)=1, so the diagonal-angle lane stride (1 row + ~1 col) sweeps
// all 32 banks instead of 16 (pitch 58 ≡ 26, gcd 2 -> systematic 4-way
// conflicts). Boxes split at 222 (not 224) so 228 B/row covers every tap
// incl. 1-ULP slop. 12928 dwords = 51712 B <= 53248 cap -> 3 blocks/CU.
#define LWPR    57                               // dwords per LDS row
#define LSTRIDE (LWPR * 4)                       // 228 B
#define LDSW    12928                            // 202 chunks of 64 dwords

typedef float vfloat2 __attribute__((ext_vector_type(2)));

// ---------------------------------------------------------------------------
// Kernel A: build padded fp8 diff image (word-granular, fully overwrites G);
// zero d_out.
// ---------------------------------------------------------------------------
__global__ __launch_bounds__(256) void pack_kernel(const float* __restrict__ a,
                                                   const float* __restrict__ b,
                                                   unsigned int* __restrict__ G,
                                                   float* __restrict__ out) {
    int i = blockIdx.x * 256 + threadIdx.x;
    if (i == 0) out[0] = 0.0f;
    if (i >= GWORDS) return;
    int pr = i / (GSTRIDE / 4);            // 116 words per padded row
    int wc = i - pr * (GSTRIDE / 4);
    int r  = pr - 8;
    int c0 = wc * 4 - 8;
    float v[4];
    #pragma unroll
    for (int j = 0; j < 4; ++j) {
        int c = c0 + j;
        float val = 0.0f;
        if ((unsigned)r < (unsigned)IMG && (unsigned)c < (unsigned)IMG) {
            int idx = r * IMG + c;
            val = a[idx] - b[idx];
        }
        v[j] = val;
    }
    unsigned int u = __builtin_amdgcn_cvt_pk_fp8_f32(v[0], v[1], 0u, false);
    u = __builtin_amdgcn_cvt_pk_fp8_f32(v[2], v[3], u, true);
    G[i] = u;
}

__global__ void zero_out_kernel(float* __restrict__ out) {
    if (threadIdx.x == 0) out[0] = 0.0f;
}

// ---------------------------------------------------------------------------
// Kernel B: block = (angle, quadrant), 448 threads. Async staging
// (global_load_lds) with the per-ray prologue (sincos + exact half-open
// clip) hoisted before the barrier so it runs under staging latency.
// Quadrant boxes split at 222; odd LDS pitch 57 kills the diagonal 4-way
// bank conflict. March: 4x ds_read_u8 + 2 HW fp8 unpacks per sample.
// Partial -> S plane (plain store, no atomics).
// ---------------------------------------------------------------------------
__global__ __launch_bounds__(448) void proj_lds(const unsigned int* __restrict__ G,
                                                float* __restrict__ S,
                                                float theta_step, float gmax,
                                                float gstep, float t0,
                                                float dtstep) {
    __shared__ unsigned int L4[LDSW];              // 51712 B -> 3 blocks/CU

    const int blk = blockIdx.x;          // 0..1279
    const int a  = blk >> 2;
    const int q  = blk & 3;
    const int qi = q >> 1, qj = q & 1;
    const int r0 = qi ? 220 : -2;        // first staged pixel row
    const int c0 = qj ? 216 : -4;        // first staged pixel col (word-aligned)
    const int nrows = qi ? 200 : 226;    // box rows + tap + slop margin

    // --- async stage: 64-dword wave chunks, every LDS word written --------
    // Pad-chunk words map to G rows <= 428 < 432 (defined), so all lanes
    // stay active and every staged word is deterministic.
    {
        const int wave = threadIdx.x >> 6;
        const int lane = threadIdx.x & 63;
        const int gbase = ((r0 + 8) * GSTRIDE + (c0 + 8)) >> 2;  // word index
        const int padded = (nrows * LWPR + 63) & ~63;
        for (int base = wave * 64; base < padded; base += 448) {
            const int idx = base + lane;
            const int rr = idx / LWPR;
            const int cc = idx - rr * LWPR;
            const unsigned int* g = &G[gbase + rr * 116 + cc];
            __builtin_amdgcn_global_load_lds(
                (const __attribute__((address_space(1))) unsigned int*)g,
                (__attribute__((address_space(3))) unsigned int*)&L4[base],
                4, 0, 0);
        }
    }

    // --- prologue (overlaps staging latency; registers only) ---------------
    const int d = threadIdx.x;
    int ks = 1, ke = 0;
    float colR = 0.0f, rowR = 0.0f;
    if (d < N_DET) {
        const float theta = (float)a * theta_step;
        const float gamma = fmaf((float)d, gstep, -gmax);
        float s1, c1, s2, c2;
        sincosf(theta, &s1, &c1);
        sincosf(theta + gamma, &s2, &c2);
        const float sx = fmaf(1075.0f, c1, 207.5f);
        const float sy = fmaf(1075.0f, s1, 207.5f);

        // col(k) = C0 - k*dc ; row(k) = R0 - k*dr   (k = 0..415)
        const float C0 = fmaf(-t0, c2, sx), dc = dtstep * c2;
        const float R0 = fmaf(-t0, s2, sy), dr = dtstep * s2;

        // quadrant box, half-open at 222: col in [cl,ch), row in [rl,rh)
        const float cl = qj ? 222.0f : -2.0f, ch = qj ? 418.0f : 222.0f;
        const float rl = qi ? 222.0f : -2.0f, rh = qi ? 418.0f : 222.0f;

        int klo = 0, khi = N_SAMP - 1;
        auto clip1 = [&](float X0, float dX, float lo, float hi) {
            if (fabsf(dX) < 1e-8f) {
                if (!(X0 >= lo && X0 < hi)) { klo = 1; khi = 0; }
            } else {
                float x1 = (X0 - hi) / dX;        // strict side
                float x2 = (X0 - lo) / dX;        // inclusive side
                x1 = fminf(fmaxf(x1, -1e6f), 1e6f);
                x2 = fminf(fmaxf(x2, -1e6f), 1e6f);
                int lo_k, hi_k;
                if (dX > 0.0f) { lo_k = (int)floorf(x1) + 1; hi_k = (int)floorf(x2); }
                else           { lo_k = (int)ceilf(x2);      hi_k = (int)ceilf(x1) - 1; }
                klo = max(klo, lo_k);
                khi = min(khi, hi_k);
            }
        };
        clip1(C0, dc, cl, ch);
        clip1(R0, dr, rl, rh);
        ks = klo; ke = khi;

        // LDS-relative coords (low-side 1-ULP slop is benign: trunc clamps
        // -eps to 0 with a ~1e-7 negative weight on valid taps)
        colR = fmaf(-(float)klo, dc, C0) - (float)c0;
        rowR = fmaf(-(float)klo, dr, R0) - (float)r0;
    }

    __syncthreads();   // drains vmcnt (async stages) before any LDS read

    if (d < N_DET) {
        // recompute steps (cheap, keeps live-range across barrier minimal)
        const float gamma = fmaf((float)d, gstep, -gmax);
        const float theta = (float)a * theta_step;
        float s2, c2;
        sincosf(theta + gamma, &s2, &c2);
        const float dc = dtstep * c2;
        const float dr = dtstep * s2;

        const unsigned char* L = (const unsigned char*)L4;
        float acc = 0.0f;
        if (ks <= ke) {
            #pragma unroll 4
            for (int k = ks; k <= ke; ++k) {
                const int ci = (int)colR;
                const int ri = (int)rowR;
                const float wc = colR - (float)ci;
                const float wr = rowR - (float)ri;
                const int base = ri * LSTRIDE + ci;
                const unsigned int b00 = L[base];
                const unsigned int b01 = L[base + 1];
                const unsigned int b10 = L[base + LSTRIDE];
                const unsigned int b11 = L[base + LSTRIDE + 1];
                const vfloat2 lo2 = __builtin_amdgcn_cvt_pk_f32_fp8(b00 | (b01 << 8), false);
                const vfloat2 hi2 = __builtin_amdgcn_cvt_pk_f32_fp8(b10 | (b11 << 8), false);
                const float top = fmaf(wc, lo2[1] - lo2[0], lo2[0]);
                const float bot = fmaf(wc, hi2[1] - hi2[0], hi2[0]);
                acc = fmaf(wr, bot - top, acc + top);
                colR -= dc;
                rowR -= dr;
            }
        }
        S[q * SPLANE + a * N_DET + d] = acc;
    }
}

// ---------------------------------------------------------------------------
// Kernel C: combine the 4 quadrant partials per ray, square, reduce, scale.
// ---------------------------------------------------------------------------
__global__ __launch_bounds__(256) void reduce_kernel(const float* __restrict__ S,
                                                     float* __restrict__ out,
                                                     float coef) {
    const int i = blockIdx.x * 256 + threadIdx.x;
    float v = 0.0f;
    if (i < SPLANE)
        v = (S[i] + S[SPLANE + i]) + (S[2 * SPLANE + i] + S[3 * SPLANE + i]);
    float sq = v * v;
    #pragma unroll
    for (int m = 32; m > 0; m >>= 1) sq += __shfl_down(sq, m, 64);
    __shared__ float w[4];
    const int lane = threadIdx.x & 63;
    if (lane == 0) w[threadIdx.x >> 6] = sq;
    __syncthreads();
    if (threadIdx.x == 0)
        atomicAdd(out, (w[0] + w[1] + w[2] + w[3]) * coef);
}

// ---------------------------------------------------------------------------
// Fallback (ws too small): fused one-thread-per-ray fp32 gather version.
// ---------------------------------------------------------------------------
__global__ __launch_bounds__(256) void proj_fused(const float* __restrict__ imgA,
                                                  const float* __restrict__ imgB,
                                                  float* __restrict__ out,
                                                  float theta_step, float gmax,
                                                  float gstep, float t0,
                                                  float dtstep, float coef) {
    const int idx = blockIdx.x * 256 + threadIdx.x;
    const int a  = idx / N_DET;
    const int dd = idx - a * N_DET;
    const float theta = (float)a * theta_step;
    const float gamma = fmaf((float)dd, gstep, -gmax);
    float s1, c1, s2, c2;
    sincosf(theta, &s1, &c1);
    sincosf(theta + gamma, &s2, &c2);
    const float sx = 1075.0f * c1 + 207.5f;
    const float sy = 1075.0f * s1 + 207.5f;
    float acc = 0.0f;
    #pragma unroll 4
    for (int s = 0; s < N_SAMP; ++s) {
        const float t   = fmaf((float)s, dtstep, t0);
        const float col = fmaf(-t, c2, sx);
        const float row = fmaf(-t, s2, sy);
        const float c0 = floorf(col);
        const float r0 = floorf(row);
        const float wc = col - c0;
        const float wr = row - r0;
        const int ci = (int)c0;
        const int ri = (int)r0;
        auto Gv = [&](int r, int c) -> float {
            if ((unsigned)r < (unsigned)IMG && (unsigned)c < (unsigned)IMG)
                return imgA[r * IMG + c] - imgB[r * IMG + c];
            return 0.0f;
        };
        const float v00 = Gv(ri, ci);
        const float v01 = Gv(ri, ci + 1);
        const float v10 = Gv(ri + 1, ci);
        const float v11 = Gv(ri + 1, ci + 1);
        const float top = fmaf(wc, v01 - v00, v00);
        const float bot = fmaf(wc, v11 - v10, v10);
        acc += fmaf(wr, bot - top, top);
    }
    float sq = acc * acc;
    #pragma unroll
    for (int o = 32; o > 0; o >>= 1) sq += __shfl_down(sq, o, 64);
    __shared__ float wsum[4];
    const int lane = threadIdx.x & 63;
    if (lane == 0) wsum[threadIdx.x >> 6] = sq;
    __syncthreads();
    if (threadIdx.x == 0)
        atomicAdd(out, (wsum[0] + wsum[1] + wsum[2] + wsum[3]) * coef);
}

extern "C" void kernel_launch(void* const* d_in, const int* in_sizes, int n_in,
                              void* d_out, int out_size, void* d_ws, size_t ws_size,
                              hipStream_t stream) {
    const float* in = (const float*)d_in[0];
    const float* tg = (const float*)d_in[1];
    float* out = (float*)d_out;

    const double half_diag = (IMG / 2.0) * sqrt(2.0);
    const double ray_len   = IMG * sqrt(2.0);
    const float  gmax      = (float)asin(half_diag / 1075.0);
    const float  gstep     = (float)(2.0 * (double)gmax / (N_DET - 1));
    const float  t0        = (float)(1075.0 - ray_len / 2.0);
    const float  dtstep    = (float)(ray_len / (N_SAMP - 1));
    const float  theta_step = (float)(2.0 * M_PI / N_ANG);
    const double dt        = ray_len / (N_SAMP - 1);
    const double SCALE     = 512.0 / 416.0 * 0.03;
    const float  coef      = (float)(dt * dt * SCALE / ((double)N_ANG * N_DET));

    if (ws_size >= WSNEED) {
        unsigned int* G = (unsigned int*)d_ws;
        float* S = (float*)((char*)d_ws + GBYTES);
        pack_kernel<<<(GWORDS + 255) / 256, 256, 0, stream>>>(in, tg, G, out);
        proj_lds<<<N_ANG * 4, 448, 0, stream>>>(G, S, theta_step, gmax, gstep,
                                                t0, dtstep);
        reduce_kernel<<<SPLANE / 256, 256, 0, stream>>>(S, out, coef);
    } else {
        zero_out_kernel<<<1, 64, 0, stream>>>(out);
        proj_fused<<<(N_ANG * N_DET) / 256, 256, 0, stream>>>(
            in, tg, out, theta_step, gmax, gstep, t0, dtstep, coef);
    }
}

// Round 10
// 103.679 us; speedup vs baseline: 1.0310x; 1.0310x over previous
//
#include <hip/hip_runtime.h>
#include <math.h>

#define IMG 416
#define N_ANG 320
#define N_DET 416
#define N_SAMP 416

// ---------------------------------------------------------------------------
// Padded global fp8 image G: stride 464 B, 432 rows. Pixel (r,c) of the diff
// image lives at G[(r+8)*464 + (c+8)], zero outside [0,416)^2.
// ---------------------------------------------------------------------------
#define GSTRIDE 464
#define GROWS   432
#define GBYTES  ((size_t)GROWS * GSTRIDE)        // 200448
#define GWORDS  (GROWS * GSTRIDE / 4)            // 50112

#define SPLANE  (N_ANG * N_DET)                  // 133120 rays
#define SBYTES  ((size_t)4 * SPLANE * sizeof(float))
#define WSNEED  (GBYTES + SBYTES)

// LDS staged quadrant tile: up to 228 rows x 58 dwords (232 B pitch, R0
// layout), staged in 64-dword wave chunks via async global_load_lds.
// 13248 dwords = 52992 B <= 53248 B cap -> 3 blocks/CU (2KB granularity).
#define LWPR    58                               // dwords per LDS row
#define LSTRIDE (LWPR * 4)                       // 232 B
#define LDSW    13248                            // 207 chunks of 64 dwords

typedef float vfloat2 __attribute__((ext_vector_type(2)));

// ---------------------------------------------------------------------------
// Kernel A: build padded fp8 diff image (word-granular, fully overwrites G);
// zero d_out.
// ---------------------------------------------------------------------------
__global__ __launch_bounds__(256) void pack_kernel(const float* __restrict__ a,
                                                   const float* __restrict__ b,
                                                   unsigned int* __restrict__ G,
                                                   float* __restrict__ out) {
    int i = blockIdx.x * 256 + threadIdx.x;
    if (i == 0) out[0] = 0.0f;
    if (i >= GWORDS) return;
    int pr = i / (GSTRIDE / 4);            // 116 words per padded row
    int wc = i - pr * (GSTRIDE / 4);
    int r  = pr - 8;
    int c0 = wc * 4 - 8;
    float v[4];
    #pragma unroll
    for (int j = 0; j < 4; ++j) {
        int c = c0 + j;
        float val = 0.0f;
        if ((unsigned)r < (unsigned)IMG && (unsigned)c < (unsigned)IMG) {
            int idx = r * IMG + c;
            val = a[idx] - b[idx];
        }
        v[j] = val;
    }
    unsigned int u = __builtin_amdgcn_cvt_pk_fp8_f32(v[0], v[1], 0u, false);
    u = __builtin_amdgcn_cvt_pk_fp8_f32(v[2], v[3], u, true);
    G[i] = u;
}

__global__ void zero_out_kernel(float* __restrict__ out) {
    if (threadIdx.x == 0) out[0] = 0.0f;
}

// ---------------------------------------------------------------------------
// Kernel B: block = (angle, quadrant), 448 threads (R0 geometry, R0 march).
// Staging is ASYNC (global_load_lds, no VGPR round trip, no per-iter vmcnt
// stall) and the per-ray prologue (sincos + exact half-open clip) executes
// UNDER the staging latency, before the barrier. March: 4x ds_read_u8 +
// 2 HW fp8 unpacks per sample. Partial -> S plane (plain store, no atomics).
// ---------------------------------------------------------------------------
__global__ __launch_bounds__(448) void proj_lds(const unsigned int* __restrict__ G,
                                                float* __restrict__ S,
                                                float theta_step, float gmax,
                                                float gstep, float t0,
                                                float dtstep) {
    __shared__ unsigned int L4[LDSW];              // 52992 B -> 3 blocks/CU

    const int blk = blockIdx.x;          // 0..1279
    const int a  = blk >> 2;
    const int q  = blk & 3;
    const int qi = q >> 1, qj = q & 1;
    const int r0 = qi ? 222 : -2;        // first staged pixel row
    const int c0 = qj ? 220 : -4;        // first staged pixel col (word-aligned)
    const int nrows = qi ? 198 : 228;    // box rows + 1 safety row

    // --- async stage: 64-dword wave chunks, every LDS word written --------
    // Chunk words beyond nrows*58 map to G rows <= 234 < 432 (defined), so
    // all lanes stay active and all staged words are deterministic.
    {
        const int wave = threadIdx.x >> 6;
        const int lane = threadIdx.x & 63;
        const int gbase = ((r0 + 8) * GSTRIDE + (c0 + 8)) >> 2;  // word index
        const int padded = (nrows * LWPR + 63) & ~63;
        for (int base = wave * 64; base < padded; base += 448) {
            const int idx = base + lane;
            const int rr = idx / LWPR;
            const int cc = idx - rr * LWPR;
            const unsigned int* g = &G[gbase + rr * 116 + cc];
            __builtin_amdgcn_global_load_lds(
                (const __attribute__((address_space(1))) unsigned int*)g,
                (__attribute__((address_space(3))) unsigned int*)&L4[base],
                4, 0, 0);
        }
    }

    // --- prologue (overlaps staging latency; registers only) ---------------
    const int d = threadIdx.x;
    int ks = 1, ke = 0;
    float colR = 0.0f, rowR = 0.0f;
    if (d < N_DET) {
        const float theta = (float)a * theta_step;
        const float gamma = fmaf((float)d, gstep, -gmax);
        float s1, c1, s2, c2;
        sincosf(theta, &s1, &c1);
        sincosf(theta + gamma, &s2, &c2);
        const float sx = fmaf(1075.0f, c1, 207.5f);
        const float sy = fmaf(1075.0f, s1, 207.5f);

        // col(k) = C0 - k*dc ; row(k) = R0 - k*dr   (k = 0..415)
        const float C0 = fmaf(-t0, c2, sx), dc = dtstep * c2;
        const float R0 = fmaf(-t0, s2, sy), dr = dtstep * s2;

        // quadrant box, half-open: col in [cl,ch), row in [rl,rh)
        const float cl = qj ? 224.0f : -2.0f, ch = qj ? 418.0f : 224.0f;
        const float rl = qi ? 224.0f : -2.0f, rh = qi ? 418.0f : 224.0f;

        int klo = 0, khi = N_SAMP - 1;
        auto clip1 = [&](float X0, float dX, float lo, float hi) {
            if (fabsf(dX) < 1e-8f) {
                if (!(X0 >= lo && X0 < hi)) { klo = 1; khi = 0; }
            } else {
                float x1 = (X0 - hi) / dX;        // strict side
                float x2 = (X0 - lo) / dX;        // inclusive side
                x1 = fminf(fmaxf(x1, -1e6f), 1e6f);
                x2 = fminf(fmaxf(x2, -1e6f), 1e6f);
                int lo_k, hi_k;
                if (dX > 0.0f) { lo_k = (int)floorf(x1) + 1; hi_k = (int)floorf(x2); }
                else           { lo_k = (int)ceilf(x2);      hi_k = (int)ceilf(x1) - 1; }
                klo = max(klo, lo_k);
                khi = min(khi, hi_k);
            }
        };
        clip1(C0, dc, cl, ch);
        clip1(R0, dr, rl, rh);
        ks = klo; ke = khi;

        // LDS-relative coords (always >= 0 inside the box -> trunc==floor)
        colR = fmaf(-(float)klo, dc, C0) - (float)c0;
        rowR = fmaf(-(float)klo, dr, R0) - (float)r0;
    }

    __syncthreads();   // drains vmcnt (async stages) before any LDS read

    if (d < N_DET) {
        // recompute steps (cheap, keeps live-range across barrier minimal)
        const float gamma = fmaf((float)d, gstep, -gmax);
        const float theta = (float)a * theta_step;
        float s2, c2;
        sincosf(theta + gamma, &s2, &c2);
        const float dc = dtstep * c2;
        const float dr = dtstep * s2;

        const unsigned char* L = (const unsigned char*)L4;
        float acc = 0.0f;
        if (ks <= ke) {
            #pragma unroll 4
            for (int k = ks; k <= ke; ++k) {
                const int ci = (int)colR;
                const int ri = (int)rowR;
                const float wc = colR - (float)ci;
                const float wr = rowR - (float)ri;
                const int base = ri * LSTRIDE + ci;
                const unsigned int b00 = L[base];
                const unsigned int b01 = L[base + 1];
                const unsigned int b10 = L[base + LSTRIDE];
                const unsigned int b11 = L[base + LSTRIDE + 1];
                const vfloat2 lo2 = __builtin_amdgcn_cvt_pk_f32_fp8(b00 | (b01 << 8), false);
                const vfloat2 hi2 = __builtin_amdgcn_cvt_pk_f32_fp8(b10 | (b11 << 8), false);
                const float top = fmaf(wc, lo2[1] - lo2[0], lo2[0]);
                const float bot = fmaf(wc, hi2[1] - hi2[0], hi2[0]);
                acc = fmaf(wr, bot - top, acc + top);
                colR -= dc;
                rowR -= dr;
            }
        }
        S[q * SPLANE + a * N_DET + d] = acc;
    }
}

// ---------------------------------------------------------------------------
// Kernel C: combine the 4 quadrant partials per ray, square, reduce, scale.
// ---------------------------------------------------------------------------
__global__ __launch_bounds__(256) void reduce_kernel(const float* __restrict__ S,
                                                     float* __restrict__ out,
                                                     float coef) {
    const int i = blockIdx.x * 256 + threadIdx.x;
    float v = 0.0f;
    if (i < SPLANE)
        v = (S[i] + S[SPLANE + i]) + (S[2 * SPLANE + i] + S[3 * SPLANE + i]);
    float sq = v * v;
    #pragma unroll
    for (int m = 32; m > 0; m >>= 1) sq += __shfl_down(sq, m, 64);
    __shared__ float w[4];
    const int lane = threadIdx.x & 63;
    if (lane == 0) w[threadIdx.x >> 6] = sq;
    __syncthreads();
    if (threadIdx.x == 0)
        atomicAdd(out, (w[0] + w[1] + w[2] + w[3]) * coef);
}

// ---------------------------------------------------------------------------
// Fallback (ws too small): fused one-thread-per-ray fp32 gather version.
// ---------------------------------------------------------------------------
__global__ __launch_bounds__(256) void proj_fused(const float* __restrict__ imgA,
                                                  const float* __restrict__ imgB,
                                                  float* __restrict__ out,
                                                  float theta_step, float gmax,
                                                  float gstep, float t0,
                                                  float dtstep, float coef) {
    const int idx = blockIdx.x * 256 + threadIdx.x;
    const int a  = idx / N_DET;
    const int dd = idx - a * N_DET;
    const float theta = (float)a * theta_step;
    const float gamma = fmaf((float)dd, gstep, -gmax);
    float s1, c1, s2, c2;
    sincosf(theta, &s1, &c1);
    sincosf(theta + gamma, &s2, &c2);
    const float sx = 1075.0f * c1 + 207.5f;
    const float sy = 1075.0f * s1 + 207.5f;
    float acc = 0.0f;
    #pragma unroll 4
    for (int s = 0; s < N_SAMP; ++s) {
        const float t   = fmaf((float)s, dtstep, t0);
        const float col = fmaf(-t, c2, sx);
        const float row = fmaf(-t, s2, sy);
        const float c0 = floorf(col);
        const float r0 = floorf(row);
        const float wc = col - c0;
        const float wr = row - r0;
        const int ci = (int)c0;
        const int ri = (int)r0;
        auto Gv = [&](int r, int c) -> float {
            if ((unsigned)r < (unsigned)IMG && (unsigned)c < (unsigned)IMG)
                return imgA[r * IMG + c] - imgB[r * IMG + c];
            return 0.0f;
        };
        const float v00 = Gv(ri, ci);
        const float v01 = Gv(ri, ci + 1);
        const float v10 = Gv(ri + 1, ci);
        const float v11 = Gv(ri + 1, ci + 1);
        const float top = fmaf(wc, v01 - v00, v00);
        const float bot = fmaf(wc, v11 - v10, v10);
        acc += fmaf(wr, bot - top, top);
    }
    float sq = acc * acc;
    #pragma unroll
    for (int o = 32; o > 0; o >>= 1) sq += __shfl_down(sq, o, 64);
    __shared__ float wsum[4];
    const int lane = threadIdx.x & 63;
    if (lane == 0) wsum[threadIdx.x >> 6] = sq;
    __syncthreads();
    if (threadIdx.x == 0)
        atomicAdd(out, (wsum[0] + wsum[1] + wsum[2] + wsum[3]) * coef);
}

extern "C" void kernel_launch(void* const* d_in, const int* in_sizes, int n_in,
                              void* d_out, int out_size, void* d_ws, size_t ws_size,
                              hipStream_t stream) {
    const float* in = (const float*)d_in[0];
    const float* tg = (const float*)d_in[1];
    float* out = (float*)d_out;

    const double half_diag = (IMG / 2.0) * sqrt(2.0);
    const double ray_len   = IMG * sqrt(2.0);
    const float  gmax      = (float)asin(half_diag / 1075.0);
    const float  gstep     = (float)(2.0 * (double)gmax / (N_DET - 1));
    const float  t0        = (float)(1075.0 - ray_len / 2.0);
    const float  dtstep    = (float)(ray_len / (N_SAMP - 1));
    const float  theta_step = (float)(2.0 * M_PI / N_ANG);
    const double dt        = ray_len / (N_SAMP - 1);
    const double SCALE     = 512.0 / 416.0 * 0.03;
    const float  coef      = (float)(dt * dt * SCALE / ((double)N_ANG * N_DET));

    if (ws_size >= WSNEED) {
        unsigned int* G = (unsigned int*)d_ws;
        float* S = (float*)((char*)d_ws + GBYTES);
        pack_kernel<<<(GWORDS + 255) / 256, 256, 0, stream>>>(in, tg, G, out);
        proj_lds<<<N_ANG * 4, 448, 0, stream>>>(G, S, theta_step, gmax, gstep,
                                                t0, dtstep);
        reduce_kernel<<<SPLANE / 256, 256, 0, stream>>>(S, out, coef);
    } else {
        zero_out_kernel<<<1, 64, 0, stream>>>(out);
        proj_fused<<<(N_ANG * N_DET) / 256, 256, 0, stream>>>(
            in, tg, out, theta_step, gmax, gstep, t0, dtstep, coef);
    }
}